// Round 10
// baseline (176.248 us; speedup 1.0000x reference)
//
#include <hip/hip_runtime.h>
#include <hip/hip_bf16.h>

#define NN 50000      // nodes
#define NM 10000      // hyperedges
#define NE 500000     // incidences
#define CAPH 128      // fixed bin capacity per hedge (mean 50, sd 7 -> 11 sd)
#define CAPN 32       // fixed bin capacity per node  (mean 10, sd 3.2 -> 7 sd)
#define SPCAP 4096    // spill safety list

// phase1 merged-kernel role partition: XCD-partitioned binning || MFMA GEMM || er rows
#define BIN_BLK   240                        // 30 blocks per presumed XCD
#define GEMM_TILES ((NN + 63) / 64)          // 782
#define ROWS_BLK  300
#define P1_GRID   (BIN_BLK + GEMM_TILES + ROWS_BLK)

typedef short bf16x8 __attribute__((ext_vector_type(8)));
typedef unsigned short u16x8 __attribute__((ext_vector_type(8)));
typedef float f32x4 __attribute__((ext_vector_type(4)));

// ---------------- workspace layout ----------------
// float-sized slots:
//   vke(bf16 u32x64/row) 3,200,000 @ 0
//   ekv(bf16 u32x64/row)   640,000 @ 3,200,000
//   el      100,000 @ 3,840,000
//   er       20,000 @ 3,940,000
//   el2      20,000 @ 3,960,000
//   er2     100,000 @ 3,980,000
//   cqe         256 @ 4,080,000
//   cqv         256 @ 4,080,256
//   Wt (bf16 16384)  8,192 float slots @ 4,080,512
// ints (base = float offset 4,089,000):
//   cur      60,000 @ 0   (hedge cursors then node cursors)
//   spc_h         1 @ 60,000
//   spc_n         1 @ 60,001
//   csrH  1,280,000 u16 = 640,000 int @ 60,004
//   csrN  1,600,000 u16 = 800,000 int @ 700,004
//   spill_h  4096 int2 = 8,192 int @ 1,500,004
//   spill_n  4096 int2 = 8,192 int @ 1,508,196
static const size_t OFF_VKE  = 0;
static const size_t OFF_EKV  = 3200000;
static const size_t OFF_EL   = 3840000;
static const size_t OFF_ER   = 3940000;
static const size_t OFF_EL2  = 3960000;
static const size_t OFF_ER2  = 3980000;
static const size_t OFF_CQE  = 4080000;
static const size_t OFF_CQV  = 4080256;
static const size_t OFF_WT   = 4080512;
static const size_t OFF_INT  = 4089000;
static const size_t I_CUR    = 0;
static const size_t I_SPCH   = 60000;
static const size_t I_SPCN   = 60001;
static const size_t I_CSRH   = 60004;
static const size_t I_CSRN   = 700004;
static const size_t I_SPH    = 1500004;
static const size_t I_SPN    = 1508196;

__device__ __forceinline__ unsigned short f2bf(float f) {
    unsigned int u = __float_as_uint(f);
    unsigned int r = (u + 0x7fffu + ((u >> 16) & 1u)) >> 16;   // RNE
    return (unsigned short)r;
}
__device__ __forceinline__ float bflo(unsigned int p) { return __uint_as_float(p << 16); }
__device__ __forceinline__ float bfhi(unsigned int p) { return __uint_as_float(p & 0xffff0000u); }

// ---- prep: zero cursors/spill counts; blocks 0,1 = attn folds; 2..65 = Wt transpose ----
__global__ void prep_kernel(const float* __restrict__ W_qe, const float* __restrict__ attn_qe,
                            float* __restrict__ cqe,
                            const float* __restrict__ W_qv, const float* __restrict__ attn_qv,
                            float* __restrict__ cqv,
                            const float* __restrict__ W_ke, unsigned short* __restrict__ Wt,
                            int* __restrict__ cur) {
    int b = blockIdx.x, t = threadIdx.x;     // 66 blocks x 256 threads
    for (int i = b * 256 + t; i < NM + NN + 2; i += 66 * 256) cur[i] = 0;
    if (b < 2) {
        const float* W    = b ? W_qv : W_qe;
        const float* attn = b ? attn_qv : attn_qe;
        float*       c    = b ? cqv : cqe;
        int h = t >> 7, k = t & 127;
        float s = 0.f;
        #pragma unroll 8
        for (int j = 0; j < 64; ++j) s += W[k * 128 + h * 64 + j] * attn[h * 64 + j];
        c[h * 128 + k] = s;
    } else {
        int col = (b - 2) * 2 + (t >> 7), k = t & 127;
        Wt[col * 128 + k] = f2bf(W_ke[k * 128 + col]);
    }
}

// ---- phase1 merged kernel: XCD-partitioned binning || MFMA GEMM+el+er2 || er rows ----
struct P1Smem {
    unsigned short Abuf[64 * 128];   // 16 KB
    unsigned short Wbuf[128 * 128];  // 32 KB
};

__global__ __launch_bounds__(256) void phase1_kernel(
        // bin role
        const int* __restrict__ inc_n, const int* __restrict__ inc_h,
        int* __restrict__ cur,
        unsigned short* __restrict__ csrH, unsigned short* __restrict__ csrN,
        int* __restrict__ spc_h, int2* __restrict__ spill_h,
        int* __restrict__ spc_n, int2* __restrict__ spill_n,
        // gemm role
        const float* __restrict__ X, const unsigned short* __restrict__ Wt,
        const float* __restrict__ attn, const float* __restrict__ cq,
        unsigned short* __restrict__ Y, float* __restrict__ el, float* __restrict__ er2,
        // rows_dot role
        const float* __restrict__ EF, const float* __restrict__ cqe,
        float* __restrict__ er) {
    __shared__ P1Smem sm;
    int bid = blockIdx.x, tid = threadIdx.x;

    if (bid < BIN_BLK) {
        // ==== XCD-partitioned binning: group g = bid&7 owns hedge/node slices ====
        // Each group's 30 blocks grid-stride the WHOLE edge list and filter, so
        // every csr/cur line is written by exactly one (presumed) XCD -> one
        // writeback instead of cross-XCD dirty ping-pong. Wrong bid->XCD mapping
        // only costs perf, never correctness.
        int g = bid & 7;
        int kb = bid >> 3;                       // 0..29
        int h0 = g * (NM / 8), h1 = h0 + (NM / 8);
        int n0 = g * (NN / 8), n1 = n0 + (NN / 8);
        for (int t = kb * 256 + tid; t < NE; t += (BIN_BLK / 8) * 256) {
            int hd = inc_h[t];
            int n  = inc_n[t];
            if (hd >= h0 && hd < h1) {
                int rh = atomicAdd(&cur[hd], 1);
                if (rh < CAPH) csrH[hd * CAPH + rh] = (unsigned short)n;
                else { int s = atomicAdd(spc_h, 1); if (s < SPCAP) spill_h[s] = make_int2(hd, n); }
            }
            if (n >= n0 && n < n1) {
                int rn = atomicAdd(&cur[NM + n], 1);
                if (rn < CAPN) csrN[n * CAPN + rn] = (unsigned short)hd;
                else { int s = atomicAdd(spc_n, 1); if (s < SPCAP) spill_n[s] = make_int2(n, hd); }
            }
        }
        return;
    }
    if (bid >= BIN_BLK + GEMM_TILES) {
        // ================= er rows: er[m][h] = EF[m,:].cqe[h,:] =================
        int wave = tid >> 6, lane = tid & 63;
        for (int g = bid - BIN_BLK - GEMM_TILES; g < (NM + 3) / 4; g += ROWS_BLK) {
            int m = g * 4 + wave;
            if (m < NM) {
                float x0 = EF[(size_t)m * 128 + lane];
                float x1 = EF[(size_t)m * 128 + 64 + lane];
                float a0 = x0 * cqe[lane]       + x1 * cqe[64 + lane];
                float a1 = x0 * cqe[128 + lane] + x1 * cqe[192 + lane];
                for (int off = 32; off > 0; off >>= 1) {
                    a0 += __shfl_down(a0, off);
                    a1 += __shfl_down(a1, off);
                }
                if (lane == 0) { er[m * 2] = a0; er[m * 2 + 1] = a1; }
            }
        }
        return;
    }

    // ================= MFMA GEMM tile =================
    int m0 = (bid - BIN_BLK) * 64;
    const int R = NN;
    // ---- stage W (bf16 global, coalesced) ----
    {
        const u16x8* Wg = reinterpret_cast<const u16x8*>(Wt);
        #pragma unroll
        for (int i = 0; i < 8; ++i) {
            int idx16 = i * 256 + tid;           // 2048 x 16B
            u16x8 w8 = Wg[idx16];
            int col = idx16 >> 4, kb = idx16 & 15;
            int us = (col * 128 + kb * 8) ^ ((col & 7) << 3);
            *reinterpret_cast<u16x8*>(&sm.Wbuf[us]) = w8;
        }
    }
    // ---- stage X (f32 -> bf16) + er2 partial dot with cq ----
    {
        int r = tid >> 2, q = tid & 3;           // 4 threads per row, 32 cols each
        int m = m0 + r;
        float p0 = 0.f, p1 = 0.f;
        if (m < R) {
            const float4* Xr = reinterpret_cast<const float4*>(X + (size_t)m * 128 + q * 32);
            #pragma unroll
            for (int i2 = 0; i2 < 4; ++i2) {
                float4 u = Xr[i2 * 2], v = Xr[i2 * 2 + 1];
                int k0 = q * 32 + i2 * 8;
                u16x8 w8;
                w8[0] = f2bf(u.x); w8[1] = f2bf(u.y); w8[2] = f2bf(u.z); w8[3] = f2bf(u.w);
                w8[4] = f2bf(v.x); w8[5] = f2bf(v.y); w8[6] = f2bf(v.z); w8[7] = f2bf(v.w);
                int us = (r * 128 + k0) ^ ((r & 7) << 3);
                *reinterpret_cast<u16x8*>(&sm.Abuf[us]) = w8;
                p0 += u.x * cq[k0] + u.y * cq[k0 + 1] + u.z * cq[k0 + 2] + u.w * cq[k0 + 3]
                    + v.x * cq[k0 + 4] + v.y * cq[k0 + 5] + v.z * cq[k0 + 6] + v.w * cq[k0 + 7];
                p1 += u.x * cq[128 + k0] + u.y * cq[128 + k0 + 1] + u.z * cq[128 + k0 + 2] + u.w * cq[128 + k0 + 3]
                    + v.x * cq[128 + k0 + 4] + v.y * cq[128 + k0 + 5] + v.z * cq[128 + k0 + 6] + v.w * cq[128 + k0 + 7];
            }
        } else {
            u16x8 z = {0, 0, 0, 0, 0, 0, 0, 0};
            #pragma unroll
            for (int i2 = 0; i2 < 4; ++i2) {
                int us = (r * 128 + q * 32 + i2 * 8) ^ ((r & 7) << 3);
                *reinterpret_cast<u16x8*>(&sm.Abuf[us]) = z;
            }
        }
        p0 += __shfl_xor(p0, 1); p0 += __shfl_xor(p0, 2);
        p1 += __shfl_xor(p1, 1); p1 += __shfl_xor(p1, 2);
        if (q == 0 && m < R)
            reinterpret_cast<float2*>(er2 + (size_t)m * 2)[0] = make_float2(p0, p1);
    }
    __syncthreads();

    // ---- MFMA: wave w -> rows [w*16, w*16+16), 8 col-tiles, 4 K-steps ----
    int l = tid & 63, w = tid >> 6;
    int lrow = w * 16 + (l & 15);
    f32x4 acc[8];
    #pragma unroll
    for (int ct = 0; ct < 8; ++ct) acc[ct] = (f32x4){0.f, 0.f, 0.f, 0.f};
    #pragma unroll
    for (int s = 0; s < 4; ++s) {
        int aidx = (lrow * 128 + s * 32 + (l >> 4) * 8) ^ ((lrow & 7) << 3);
        bf16x8 af = *reinterpret_cast<const bf16x8*>(&sm.Abuf[aidx]);
        #pragma unroll
        for (int ct = 0; ct < 8; ++ct) {
            int col = ct * 16 + (l & 15);
            int bidx = (col * 128 + s * 32 + (l >> 4) * 8) ^ ((col & 7) << 3);
            bf16x8 bf = *reinterpret_cast<const bf16x8*>(&sm.Wbuf[bidx]);
            acc[ct] = __builtin_amdgcn_mfma_f32_16x16x32_bf16(af, bf, acc[ct], 0, 0, 0);
        }
    }

    // ---- epilogue: Y bf16 store, el reduce ----
    float av[8];
    #pragma unroll
    for (int ct = 0; ct < 8; ++ct) av[ct] = attn[ct * 16 + (l & 15)];
    #pragma unroll
    for (int r = 0; r < 4; ++r) {
        int m = m0 + w * 16 + (l >> 4) * 4 + r;
        bool ok = (m < R);
        #pragma unroll
        for (int ct = 0; ct < 8; ++ct)
            if (ok) Y[(size_t)m * 128 + ct * 16 + (l & 15)] = f2bf(acc[ct][r]);
        #pragma unroll
        for (int h = 0; h < 2; ++h) {
            float p = acc[h * 4][r] * av[h * 4] + acc[h * 4 + 1][r] * av[h * 4 + 1]
                    + acc[h * 4 + 2][r] * av[h * 4 + 2] + acc[h * 4 + 3][r] * av[h * 4 + 3];
            p += __shfl_xor(p, 1); p += __shfl_xor(p, 2);
            p += __shfl_xor(p, 4); p += __shfl_xor(p, 8);
            if ((l & 15) == 0 && ok) el[(size_t)m * 2 + h] = p;
        }
    }
}

// ---- GEMM [R,64] @ [64,128] -> Ybf16 [R,128], plus el reduce ----
template<int RPB>
__global__ void gemm64_el_kernel(const float* __restrict__ X, const float* __restrict__ W,
                                 const float* __restrict__ attn, unsigned short* __restrict__ Y,
                                 float* __restrict__ el, int R) {
    __shared__ float rows[RPB][64];
    int tid = threadIdx.x;              // 0..127
    int r0 = blockIdx.x * RPB;
    for (int i = tid; i < RPB * 64; i += 128) {
        int r = i >> 6, k = i & 63;
        int m = r0 + r;
        rows[r][k] = (m < R) ? X[(size_t)m * 64 + k] : 0.f;
    }
    __syncthreads();
    float acc[RPB];
    #pragma unroll
    for (int r = 0; r < RPB; ++r) acc[r] = 0.f;
    #pragma unroll 8
    for (int k = 0; k < 64; ++k) {
        float wv = W[k * 128 + tid];
        #pragma unroll
        for (int r = 0; r < RPB; ++r) acc[r] += rows[r][k] * wv;
    }
    float av = attn[tid];
    int h = tid >> 6;
    for (int r = 0; r < RPB; ++r) {
        int m = r0 + r;
        if (m < R) Y[(size_t)m * 128 + tid] = f2bf(acc[r]);
        float v = acc[r] * av;
        for (int off = 32; off > 0; off >>= 1) v += __shfl_down(v, off);
        if ((tid & 63) == 0 && m < R) el[m * 2 + h] = v;
    }
}

// ---- fused gather over fixed-cap bins: wave/dest, 4-way MLP unroll ----
template<int CAP>
__global__ void gather_kernel(const int* __restrict__ cnt, const unsigned short* __restrict__ csr,
                              const unsigned int* __restrict__ src32,  // [*,64] bf16x2
                              const float* __restrict__ el_src,        // [*,2]
                              const float* __restrict__ er_dst,        // [R,2]
                              const float* __restrict__ bias,          // [128]
                              const int* __restrict__ spc, const int2* __restrict__ spill,
                              float* __restrict__ out, int R) {
    int wave = threadIdx.x >> 6, lane = threadIdx.x & 63;
    int m = blockIdx.x * 4 + wave;
    if (m >= R) return;
    int h = lane >> 5;                  // lanes 0-31: head0 elems, 32-63: head1
    int c = cnt[m]; if (c > CAP) c = CAP;
    int beg = m * CAP, end = beg + c;
    float er = er_dst[m * 2 + h];
    float acc0 = 0.f, acc1 = 0.f, den = 0.f;
    int i = beg;
    for (; i + 3 < end; i += 4) {
        int vs0 = csr[i], vs1 = csr[i + 1], vs2 = csr[i + 2], vs3 = csr[i + 3];
        unsigned int p0 = src32[(size_t)vs0 * 64 + lane];
        unsigned int p1 = src32[(size_t)vs1 * 64 + lane];
        unsigned int p2 = src32[(size_t)vs2 * 64 + lane];
        unsigned int p3 = src32[(size_t)vs3 * 64 + lane];
        float ex0 = __expf(fmaxf(el_src[vs0 * 2 + h] + er, 0.f));
        float ex1 = __expf(fmaxf(el_src[vs1 * 2 + h] + er, 0.f));
        float ex2 = __expf(fmaxf(el_src[vs2 * 2 + h] + er, 0.f));
        float ex3 = __expf(fmaxf(el_src[vs3 * 2 + h] + er, 0.f));
        den += (ex0 + ex1) + (ex2 + ex3);
        acc0 += ex0 * bflo(p0) + ex1 * bflo(p1) + ex2 * bflo(p2) + ex3 * bflo(p3);
        acc1 += ex0 * bfhi(p0) + ex1 * bfhi(p1) + ex2 * bfhi(p2) + ex3 * bfhi(p3);
    }
    for (; i < end; ++i) {
        int vs = csr[i];
        unsigned int p = src32[(size_t)vs * 64 + lane];
        float ex = __expf(fmaxf(el_src[vs * 2 + h] + er, 0.f));
        den += ex;
        acc0 += ex * bflo(p);
        acc1 += ex * bfhi(p);
    }
    // spill safety (expected empty: one broadcast load)
    int sc = *spc; if (sc > SPCAP) sc = SPCAP;
    for (int s = 0; s < sc; ++s) {
        int2 pr = spill[s];
        if (pr.x == m) {
            int vs = pr.y;
            unsigned int p = src32[(size_t)vs * 64 + lane];
            float ex = __expf(fmaxf(el_src[vs * 2 + h] + er, 0.f));
            den += ex;
            acc0 += ex * bflo(p);
            acc1 += ex * bfhi(p);
        }
    }
    float inv = (den > 0.f) ? 1.f / den : 0.f;
    acc0 *= inv; acc1 *= inv;
    float b0 = __shfl_down(acc0, 32);
    float b1 = __shfl_down(acc1, 32);
    if (lane < 32) {
        int e0 = 2 * lane, e1 = 2 * lane + 1;
        float o0 = 0.5f * (acc0 + b0 + bias[e0] + bias[64 + e0]);
        float o1 = 0.5f * (acc1 + b1 + bias[e1] + bias[64 + e1]);
        reinterpret_cast<float2*>(out + (size_t)m * 64)[lane] = make_float2(o0, o1);
    }
}

extern "C" void kernel_launch(void* const* d_in, const int* in_sizes, int n_in,
                              void* d_out, int out_size, void* d_ws, size_t ws_size,
                              hipStream_t stream) {
    const float* vfeat   = (const float*)d_in[0];
    const float* efeat   = (const float*)d_in[1];
    const int*   inc_n   = (const int*)d_in[2];
    const int*   inc_h   = (const int*)d_in[3];
    const float* W_ke    = (const float*)d_in[4];
    const float* W_qe    = (const float*)d_in[5];
    const float* attn_ke = (const float*)d_in[6];
    const float* attn_qe = (const float*)d_in[7];
    const float* bias_e  = (const float*)d_in[8];
    const float* W_kv    = (const float*)d_in[9];
    const float* W_qv    = (const float*)d_in[10];
    const float* attn_kv = (const float*)d_in[11];
    const float* attn_qv = (const float*)d_in[12];
    const float* bias_v  = (const float*)d_in[13];

    float* ws = (float*)d_ws;
    unsigned int*   vke = (unsigned int*)(ws + OFF_VKE);
    unsigned int*   ekv = (unsigned int*)(ws + OFF_EKV);
    float* el   = ws + OFF_EL;
    float* er   = ws + OFF_ER;
    float* el2  = ws + OFF_EL2;
    float* er2  = ws + OFF_ER2;
    float* cqe  = ws + OFF_CQE;
    float* cqv  = ws + OFF_CQV;
    unsigned short* Wt = (unsigned short*)(ws + OFF_WT);
    int*   ib      = (int*)(ws + OFF_INT);
    int*   cur     = ib + I_CUR;
    int*   spc_h   = ib + I_SPCH;
    int*   spc_n   = ib + I_SPCN;
    unsigned short* csrH = (unsigned short*)(ib + I_CSRH);
    unsigned short* csrN = (unsigned short*)(ib + I_CSRN);
    int2*  spill_h = (int2*)(ib + I_SPH);
    int2*  spill_n = (int2*)(ib + I_SPN);

    float* out_v = (float*)d_out;                   // [50000, 64]
    float* out_e = (float*)d_out + (size_t)NN * 64; // [10000, 64]

    // ---- prep: zero cursors + attn folds + W transpose ----
    prep_kernel<<<dim3(66), dim3(256), 0, stream>>>(W_qe, attn_qe, cqe, W_qv, attn_qv, cqv,
                                                    W_ke, Wt, cur);

    // ---- phase1 merged: XCD-partitioned binning || MFMA GEMM || er rows ----
    phase1_kernel<<<dim3(P1_GRID), dim3(256), 0, stream>>>(
        inc_n, inc_h, cur, csrH, csrN, spc_h, spill_h, spc_n, spill_n,
        vfeat, Wt, attn_ke, cqv, (unsigned short*)vke, el, er2,
        efeat, cqe, er);

    // ---- Phase 1 gather: nodes -> hyperedges ----
    gather_kernel<CAPH><<<dim3((NM + 3) / 4), dim3(256), 0, stream>>>(
        cur, csrH, vke, el, er, bias_e, spc_h, spill_h, out_e, NM);

    // ---- Phase 2: hyperedges -> nodes ----
    gemm64_el_kernel<4><<<dim3((NM + 3) / 4), dim3(128), 0, stream>>>(
        out_e, W_kv, attn_kv, (unsigned short*)ekv, el2, NM);
    gather_kernel<CAPN><<<dim3((NN + 3) / 4), dim3(256), 0, stream>>>(
        cur + NM, csrN, ekv, el2, er2, bias_v, spc_n, spill_n, out_v, NN);
}

// Round 11
// 140.145 us; speedup vs baseline: 1.2576x; 1.2576x over previous
//
#include <hip/hip_runtime.h>
#include <hip/hip_bf16.h>

#define NN 50000      // nodes
#define NM 10000      // hyperedges
#define NE 500000     // incidences
#define CAPH 128      // fixed bin capacity per hedge (mean 50, sd 7 -> 11 sd)
#define CAPN 32       // fixed bin capacity per node  (mean 10, sd 3.2 -> 7 sd)
#define SPCAP 4096    // spill safety list

// phase1: hedge-binning || MFMA GEMM || er rows
#define BIN_BLK   240
#define GEMM_TILES ((NN + 63) / 64)          // 782
#define ROWS_BLK  300
#define P1_GRID   (BIN_BLK + GEMM_TILES + ROWS_BLK)

// phase2: node-binning || gather1 (+in-wave GEMV for ekv/el2)
#define BIN2_BLK  240
#define G1_BLKS   (NM / 4)                   // 2500, exact
#define P2_GRID   (BIN2_BLK + G1_BLKS)

typedef short bf16x8 __attribute__((ext_vector_type(8)));
typedef unsigned short u16x8 __attribute__((ext_vector_type(8)));
typedef float f32x4 __attribute__((ext_vector_type(4)));

// ---------------- workspace layout ----------------
// float-sized slots:
//   vke(bf16 u32x64/row) 3,200,000 @ 0
//   ekv(bf16 u32x64/row)   640,000 @ 3,200,000
//   el      100,000 @ 3,840,000
//   er       20,000 @ 3,940,000
//   el2      20,000 @ 3,960,000
//   er2     100,000 @ 3,980,000
//   cqe         256 @ 4,080,000
//   cqv         256 @ 4,080,256
//   Wt (bf16 16384)  8,192 float slots @ 4,080,512
// ints (base = float offset 4,089,000):
//   cur      60,000 @ 0   (hedge cursors then node cursors)
//   spc_h         1 @ 60,000
//   spc_n         1 @ 60,001
//   csrH  1,280,000 u16 = 640,000 int @ 60,004
//   csrN  1,600,000 u16 = 800,000 int @ 700,004
//   spill_h  4096 int2 = 8,192 int @ 1,500,004
//   spill_n  4096 int2 = 8,192 int @ 1,508,196
static const size_t OFF_VKE  = 0;
static const size_t OFF_EKV  = 3200000;
static const size_t OFF_EL   = 3840000;
static const size_t OFF_ER   = 3940000;
static const size_t OFF_EL2  = 3960000;
static const size_t OFF_ER2  = 3980000;
static const size_t OFF_CQE  = 4080000;
static const size_t OFF_CQV  = 4080256;
static const size_t OFF_WT   = 4080512;
static const size_t OFF_INT  = 4089000;
static const size_t I_CUR    = 0;
static const size_t I_SPCH   = 60000;
static const size_t I_SPCN   = 60001;
static const size_t I_CSRH   = 60004;
static const size_t I_CSRN   = 700004;
static const size_t I_SPH    = 1500004;
static const size_t I_SPN    = 1508196;

__device__ __forceinline__ unsigned short f2bf(float f) {
    unsigned int u = __float_as_uint(f);
    unsigned int r = (u + 0x7fffu + ((u >> 16) & 1u)) >> 16;   // RNE
    return (unsigned short)r;
}
__device__ __forceinline__ float bflo(unsigned int p) { return __uint_as_float(p << 16); }
__device__ __forceinline__ float bfhi(unsigned int p) { return __uint_as_float(p & 0xffff0000u); }

// ---- prep: zero cursors/spill counts; blocks 0,1 = attn folds; 2..65 = Wt transpose ----
__global__ void prep_kernel(const float* __restrict__ W_qe, const float* __restrict__ attn_qe,
                            float* __restrict__ cqe,
                            const float* __restrict__ W_qv, const float* __restrict__ attn_qv,
                            float* __restrict__ cqv,
                            const float* __restrict__ W_ke, unsigned short* __restrict__ Wt,
                            int* __restrict__ cur) {
    int b = blockIdx.x, t = threadIdx.x;     // 66 blocks x 256 threads
    for (int i = b * 256 + t; i < NM + NN + 2; i += 66 * 256) cur[i] = 0;
    if (b < 2) {
        const float* W    = b ? W_qv : W_qe;
        const float* attn = b ? attn_qv : attn_qe;
        float*       c    = b ? cqv : cqe;
        int h = t >> 7, k = t & 127;
        float s = 0.f;
        #pragma unroll 8
        for (int j = 0; j < 64; ++j) s += W[k * 128 + h * 64 + j] * attn[h * 64 + j];
        c[h * 128 + k] = s;
    } else {
        int col = (b - 2) * 2 + (t >> 7), k = t & 127;
        Wt[col * 128 + k] = f2bf(W_ke[k * 128 + col]);
    }
}

// ---- phase1 merged kernel: hedge-binning || MFMA GEMM+el+er2 || er rows ----
struct P1Smem {
    unsigned short Abuf[64 * 128];   // 16 KB
    unsigned short Wbuf[128 * 128];  // 32 KB
};

__global__ __launch_bounds__(256) void phase1_kernel(
        // hedge-bin role
        const int* __restrict__ inc_n, const int* __restrict__ inc_h,
        int* __restrict__ cur,
        unsigned short* __restrict__ csrH,
        int* __restrict__ spc_h, int2* __restrict__ spill_h,
        // gemm role
        const float* __restrict__ X, const unsigned short* __restrict__ Wt,
        const float* __restrict__ attn, const float* __restrict__ cq,
        unsigned short* __restrict__ Y, float* __restrict__ el, float* __restrict__ er2,
        // rows_dot role
        const float* __restrict__ EF, const float* __restrict__ cqe,
        float* __restrict__ er) {
    __shared__ P1Smem sm;
    int bid = blockIdx.x, tid = threadIdx.x;

    if (bid < BIN_BLK) {
        // ================= hedge binning (grid-strided over edges) =================
        for (int t = bid * 256 + tid; t < NE; t += BIN_BLK * 256) {
            int n = inc_n[t], hd = inc_h[t];
            int rh = atomicAdd(&cur[hd], 1);
            if (rh < CAPH) csrH[hd * CAPH + rh] = (unsigned short)n;
            else { int s = atomicAdd(spc_h, 1); if (s < SPCAP) spill_h[s] = make_int2(hd, n); }
        }
        return;
    }
    if (bid >= BIN_BLK + GEMM_TILES) {
        // ================= er rows: er[m][h] = EF[m,:].cqe[h,:] =================
        int wave = tid >> 6, lane = tid & 63;
        for (int g = bid - BIN_BLK - GEMM_TILES; g < (NM + 3) / 4; g += ROWS_BLK) {
            int m = g * 4 + wave;
            if (m < NM) {
                float x0 = EF[(size_t)m * 128 + lane];
                float x1 = EF[(size_t)m * 128 + 64 + lane];
                float a0 = x0 * cqe[lane]       + x1 * cqe[64 + lane];
                float a1 = x0 * cqe[128 + lane] + x1 * cqe[192 + lane];
                for (int off = 32; off > 0; off >>= 1) {
                    a0 += __shfl_down(a0, off);
                    a1 += __shfl_down(a1, off);
                }
                if (lane == 0) { er[m * 2] = a0; er[m * 2 + 1] = a1; }
            }
        }
        return;
    }

    // ================= MFMA GEMM tile =================
    int m0 = (bid - BIN_BLK) * 64;
    const int R = NN;
    // ---- stage W (bf16 global, coalesced) ----
    {
        const u16x8* Wg = reinterpret_cast<const u16x8*>(Wt);
        #pragma unroll
        for (int i = 0; i < 8; ++i) {
            int idx16 = i * 256 + tid;           // 2048 x 16B
            u16x8 w8 = Wg[idx16];
            int col = idx16 >> 4, kb = idx16 & 15;
            int us = (col * 128 + kb * 8) ^ ((col & 7) << 3);
            *reinterpret_cast<u16x8*>(&sm.Wbuf[us]) = w8;
        }
    }
    // ---- stage X (f32 -> bf16) + er2 partial dot with cq ----
    {
        int r = tid >> 2, q = tid & 3;           // 4 threads per row, 32 cols each
        int m = m0 + r;
        float p0 = 0.f, p1 = 0.f;
        if (m < R) {
            const float4* Xr = reinterpret_cast<const float4*>(X + (size_t)m * 128 + q * 32);
            #pragma unroll
            for (int i2 = 0; i2 < 4; ++i2) {
                float4 u = Xr[i2 * 2], v = Xr[i2 * 2 + 1];
                int k0 = q * 32 + i2 * 8;
                u16x8 w8;
                w8[0] = f2bf(u.x); w8[1] = f2bf(u.y); w8[2] = f2bf(u.z); w8[3] = f2bf(u.w);
                w8[4] = f2bf(v.x); w8[5] = f2bf(v.y); w8[6] = f2bf(v.z); w8[7] = f2bf(v.w);
                int us = (r * 128 + k0) ^ ((r & 7) << 3);
                *reinterpret_cast<u16x8*>(&sm.Abuf[us]) = w8;
                p0 += u.x * cq[k0] + u.y * cq[k0 + 1] + u.z * cq[k0 + 2] + u.w * cq[k0 + 3]
                    + v.x * cq[k0 + 4] + v.y * cq[k0 + 5] + v.z * cq[k0 + 6] + v.w * cq[k0 + 7];
                p1 += u.x * cq[128 + k0] + u.y * cq[128 + k0 + 1] + u.z * cq[128 + k0 + 2] + u.w * cq[128 + k0 + 3]
                    + v.x * cq[128 + k0 + 4] + v.y * cq[128 + k0 + 5] + v.z * cq[128 + k0 + 6] + v.w * cq[128 + k0 + 7];
            }
        } else {
            u16x8 z = {0, 0, 0, 0, 0, 0, 0, 0};
            #pragma unroll
            for (int i2 = 0; i2 < 4; ++i2) {
                int us = (r * 128 + q * 32 + i2 * 8) ^ ((r & 7) << 3);
                *reinterpret_cast<u16x8*>(&sm.Abuf[us]) = z;
            }
        }
        p0 += __shfl_xor(p0, 1); p0 += __shfl_xor(p0, 2);
        p1 += __shfl_xor(p1, 1); p1 += __shfl_xor(p1, 2);
        if (q == 0 && m < R)
            reinterpret_cast<float2*>(er2 + (size_t)m * 2)[0] = make_float2(p0, p1);
    }
    __syncthreads();

    // ---- MFMA: wave w -> rows [w*16, w*16+16), 8 col-tiles, 4 K-steps ----
    int l = tid & 63, w = tid >> 6;
    int lrow = w * 16 + (l & 15);
    f32x4 acc[8];
    #pragma unroll
    for (int ct = 0; ct < 8; ++ct) acc[ct] = (f32x4){0.f, 0.f, 0.f, 0.f};
    #pragma unroll
    for (int s = 0; s < 4; ++s) {
        int aidx = (lrow * 128 + s * 32 + (l >> 4) * 8) ^ ((lrow & 7) << 3);
        bf16x8 af = *reinterpret_cast<const bf16x8*>(&sm.Abuf[aidx]);
        #pragma unroll
        for (int ct = 0; ct < 8; ++ct) {
            int col = ct * 16 + (l & 15);
            int bidx = (col * 128 + s * 32 + (l >> 4) * 8) ^ ((col & 7) << 3);
            bf16x8 bf = *reinterpret_cast<const bf16x8*>(&sm.Wbuf[bidx]);
            acc[ct] = __builtin_amdgcn_mfma_f32_16x16x32_bf16(af, bf, acc[ct], 0, 0, 0);
        }
    }

    // ---- epilogue: Y bf16 store, el reduce ----
    float av[8];
    #pragma unroll
    for (int ct = 0; ct < 8; ++ct) av[ct] = attn[ct * 16 + (l & 15)];
    #pragma unroll
    for (int r = 0; r < 4; ++r) {
        int m = m0 + w * 16 + (l >> 4) * 4 + r;
        bool ok = (m < R);
        #pragma unroll
        for (int ct = 0; ct < 8; ++ct)
            if (ok) Y[(size_t)m * 128 + ct * 16 + (l & 15)] = f2bf(acc[ct][r]);
        #pragma unroll
        for (int h = 0; h < 2; ++h) {
            float p = acc[h * 4][r] * av[h * 4] + acc[h * 4 + 1][r] * av[h * 4 + 1]
                    + acc[h * 4 + 2][r] * av[h * 4 + 2] + acc[h * 4 + 3][r] * av[h * 4 + 3];
            p += __shfl_xor(p, 1); p += __shfl_xor(p, 2);
            p += __shfl_xor(p, 4); p += __shfl_xor(p, 8);
            if ((l & 15) == 0 && ok) el[(size_t)m * 2 + h] = p;
        }
    }
}

// ---- phase2 merged kernel: node-binning || gather1 + in-wave GEMV (ekv, el2) ----
__global__ __launch_bounds__(256) void phase2_kernel(
        // node-bin role
        const int* __restrict__ inc_n, const int* __restrict__ inc_h,
        int* __restrict__ cur,
        unsigned short* __restrict__ csrN,
        int* __restrict__ spc_n, int2* __restrict__ spill_n,
        // gather1 role
        const unsigned short* __restrict__ csrH,
        const unsigned int* __restrict__ vke32,
        const float* __restrict__ el, const float* __restrict__ er,
        const float* __restrict__ bias_e,
        const int* __restrict__ spc_h, const int2* __restrict__ spill_h,
        float* __restrict__ out_e,
        // GEMV
        const float* __restrict__ W_kv, const float* __restrict__ attn_kv,
        unsigned int* __restrict__ ekv32, float* __restrict__ el2) {
    int bid = blockIdx.x, tid = threadIdx.x;

    if (bid < BIN2_BLK) {
        // ================= node binning (grid-strided over edges) =================
        for (int t = bid * 256 + tid; t < NE; t += BIN2_BLK * 256) {
            int n = inc_n[t], hd = inc_h[t];
            int rn = atomicAdd(&cur[NM + n], 1);
            if (rn < CAPN) csrN[n * CAPN + rn] = (unsigned short)hd;
            else { int s = atomicAdd(spc_n, 1); if (s < SPCAP) spill_n[s] = make_int2(n, hd); }
        }
        return;
    }

    // ================= gather1: one wave per hedge (grid exact) =================
    int wave = tid >> 6, lane = tid & 63;
    int m = (bid - BIN2_BLK) * 4 + wave;          // < NM
    int h = lane >> 5;
    int c = cur[m]; if (c > CAPH) c = CAPH;
    int beg = m * CAPH, end = beg + c;
    float erv = er[m * 2 + h];
    float acc0 = 0.f, acc1 = 0.f, den = 0.f;
    int i = beg;
    for (; i + 3 < end; i += 4) {
        int vs0 = csrH[i], vs1 = csrH[i + 1], vs2 = csrH[i + 2], vs3 = csrH[i + 3];
        unsigned int p0 = vke32[(size_t)vs0 * 64 + lane];
        unsigned int p1 = vke32[(size_t)vs1 * 64 + lane];
        unsigned int p2 = vke32[(size_t)vs2 * 64 + lane];
        unsigned int p3 = vke32[(size_t)vs3 * 64 + lane];
        float ex0 = __expf(fmaxf(el[vs0 * 2 + h] + erv, 0.f));
        float ex1 = __expf(fmaxf(el[vs1 * 2 + h] + erv, 0.f));
        float ex2 = __expf(fmaxf(el[vs2 * 2 + h] + erv, 0.f));
        float ex3 = __expf(fmaxf(el[vs3 * 2 + h] + erv, 0.f));
        den += (ex0 + ex1) + (ex2 + ex3);
        acc0 += ex0 * bflo(p0) + ex1 * bflo(p1) + ex2 * bflo(p2) + ex3 * bflo(p3);
        acc1 += ex0 * bfhi(p0) + ex1 * bfhi(p1) + ex2 * bfhi(p2) + ex3 * bfhi(p3);
    }
    for (; i < end; ++i) {
        int vs = csrH[i];
        unsigned int p = vke32[(size_t)vs * 64 + lane];
        float ex = __expf(fmaxf(el[vs * 2 + h] + erv, 0.f));
        den += ex;
        acc0 += ex * bflo(p);
        acc1 += ex * bfhi(p);
    }
    // spill safety (expected empty)
    int sc = *spc_h; if (sc > SPCAP) sc = SPCAP;
    for (int s = 0; s < sc; ++s) {
        int2 pr = spill_h[s];
        if (pr.x == m) {
            int vs = pr.y;
            unsigned int p = vke32[(size_t)vs * 64 + lane];
            float ex = __expf(fmaxf(el[vs * 2 + h] + erv, 0.f));
            den += ex;
            acc0 += ex * bflo(p);
            acc1 += ex * bfhi(p);
        }
    }
    float inv = (den > 0.f) ? 1.f / den : 0.f;
    acc0 *= inv; acc1 *= inv;
    float b0 = __shfl_down(acc0, 32);
    float b1 = __shfl_down(acc1, 32);
    int e0 = 2 * (lane & 31), e1 = e0 + 1;
    // o0/o1 meaningful only in lanes<32 (row cols e0,e1); other lanes hold garbage
    float o0 = 0.5f * (acc0 + b0 + bias_e[e0] + bias_e[64 + e0]);
    float o1 = 0.5f * (acc1 + b1 + bias_e[e1] + bias_e[64 + e1]);
    if (lane < 32)
        reinterpret_cast<float2*>(out_e + (size_t)m * 64)[lane] = make_float2(o0, o1);

    // ---- in-wave GEMV: ekv[m][2l,2l+1] = sum_k row[k] * W_kv[k][2l,2l+1] ----
    const float2* Wkv2 = reinterpret_cast<const float2*>(W_kv);
    float g0 = 0.f, g1 = 0.f;
    #pragma unroll
    for (int k = 0; k < 64; ++k) {
        float rk = __shfl((k & 1) ? o1 : o0, k >> 1);   // row[k] from lane k/2
        float2 wv = Wkv2[k * 64 + lane];
        g0 += rk * wv.x;
        g1 += rk * wv.y;
    }
    ekv32[(size_t)m * 64 + lane] = ((unsigned int)f2bf(g1) << 16) | (unsigned int)f2bf(g0);
    // el2[m][h] over cols 2l,2l+1 (head = lane>>5); reduce within 32-lane half
    float p = g0 * attn_kv[2 * lane] + g1 * attn_kv[2 * lane + 1];
    p += __shfl_xor(p, 1); p += __shfl_xor(p, 2); p += __shfl_xor(p, 4);
    p += __shfl_xor(p, 8); p += __shfl_xor(p, 16);
    if ((lane & 31) == 0) el2[m * 2 + (lane >> 5)] = p;
}

// ---- final gather over node bins: wave/dest, 4-way MLP unroll ----
template<int CAP>
__global__ void gather_kernel(const int* __restrict__ cnt, const unsigned short* __restrict__ csr,
                              const unsigned int* __restrict__ src32,  // [*,64] bf16x2
                              const float* __restrict__ el_src,        // [*,2]
                              const float* __restrict__ er_dst,        // [R,2]
                              const float* __restrict__ bias,          // [128]
                              const int* __restrict__ spc, const int2* __restrict__ spill,
                              float* __restrict__ out, int R) {
    int wave = threadIdx.x >> 6, lane = threadIdx.x & 63;
    int m = blockIdx.x * 4 + wave;
    if (m >= R) return;
    int h = lane >> 5;
    int c = cnt[m]; if (c > CAP) c = CAP;
    int beg = m * CAP, end = beg + c;
    float er = er_dst[m * 2 + h];
    float acc0 = 0.f, acc1 = 0.f, den = 0.f;
    int i = beg;
    for (; i + 3 < end; i += 4) {
        int vs0 = csr[i], vs1 = csr[i + 1], vs2 = csr[i + 2], vs3 = csr[i + 3];
        unsigned int p0 = src32[(size_t)vs0 * 64 + lane];
        unsigned int p1 = src32[(size_t)vs1 * 64 + lane];
        unsigned int p2 = src32[(size_t)vs2 * 64 + lane];
        unsigned int p3 = src32[(size_t)vs3 * 64 + lane];
        float ex0 = __expf(fmaxf(el_src[vs0 * 2 + h] + er, 0.f));
        float ex1 = __expf(fmaxf(el_src[vs1 * 2 + h] + er, 0.f));
        float ex2 = __expf(fmaxf(el_src[vs2 * 2 + h] + er, 0.f));
        float ex3 = __expf(fmaxf(el_src[vs3 * 2 + h] + er, 0.f));
        den += (ex0 + ex1) + (ex2 + ex3);
        acc0 += ex0 * bflo(p0) + ex1 * bflo(p1) + ex2 * bflo(p2) + ex3 * bflo(p3);
        acc1 += ex0 * bfhi(p0) + ex1 * bfhi(p1) + ex2 * bfhi(p2) + ex3 * bfhi(p3);
    }
    for (; i < end; ++i) {
        int vs = csr[i];
        unsigned int p = src32[(size_t)vs * 64 + lane];
        float ex = __expf(fmaxf(el_src[vs * 2 + h] + er, 0.f));
        den += ex;
        acc0 += ex * bflo(p);
        acc1 += ex * bfhi(p);
    }
    int sc = *spc; if (sc > SPCAP) sc = SPCAP;
    for (int s = 0; s < sc; ++s) {
        int2 pr = spill[s];
        if (pr.x == m) {
            int vs = pr.y;
            unsigned int p = src32[(size_t)vs * 64 + lane];
            float ex = __expf(fmaxf(el_src[vs * 2 + h] + er, 0.f));
            den += ex;
            acc0 += ex * bflo(p);
            acc1 += ex * bfhi(p);
        }
    }
    float inv = (den > 0.f) ? 1.f / den : 0.f;
    acc0 *= inv; acc1 *= inv;
    float b0 = __shfl_down(acc0, 32);
    float b1 = __shfl_down(acc1, 32);
    if (lane < 32) {
        int e0 = 2 * lane, e1 = 2 * lane + 1;
        float o0 = 0.5f * (acc0 + b0 + bias[e0] + bias[64 + e0]);
        float o1 = 0.5f * (acc1 + b1 + bias[e1] + bias[64 + e1]);
        reinterpret_cast<float2*>(out + (size_t)m * 64)[lane] = make_float2(o0, o1);
    }
}

extern "C" void kernel_launch(void* const* d_in, const int* in_sizes, int n_in,
                              void* d_out, int out_size, void* d_ws, size_t ws_size,
                              hipStream_t stream) {
    const float* vfeat   = (const float*)d_in[0];
    const float* efeat   = (const float*)d_in[1];
    const int*   inc_n   = (const int*)d_in[2];
    const int*   inc_h   = (const int*)d_in[3];
    const float* W_ke    = (const float*)d_in[4];
    const float* W_qe    = (const float*)d_in[5];
    const float* attn_ke = (const float*)d_in[6];
    const float* attn_qe = (const float*)d_in[7];
    const float* bias_e  = (const float*)d_in[8];
    const float* W_kv    = (const float*)d_in[9];
    const float* W_qv    = (const float*)d_in[10];
    const float* attn_kv = (const float*)d_in[11];
    const float* attn_qv = (const float*)d_in[12];
    const float* bias_v  = (const float*)d_in[13];

    float* ws = (float*)d_ws;
    unsigned int*   vke = (unsigned int*)(ws + OFF_VKE);
    unsigned int*   ekv = (unsigned int*)(ws + OFF_EKV);
    float* el   = ws + OFF_EL;
    float* er   = ws + OFF_ER;
    float* el2  = ws + OFF_EL2;
    float* er2  = ws + OFF_ER2;
    float* cqe  = ws + OFF_CQE;
    float* cqv  = ws + OFF_CQV;
    unsigned short* Wt = (unsigned short*)(ws + OFF_WT);
    int*   ib      = (int*)(ws + OFF_INT);
    int*   cur     = ib + I_CUR;
    int*   spc_h   = ib + I_SPCH;
    int*   spc_n   = ib + I_SPCN;
    unsigned short* csrH = (unsigned short*)(ib + I_CSRH);
    unsigned short* csrN = (unsigned short*)(ib + I_CSRN);
    int2*  spill_h = (int2*)(ib + I_SPH);
    int2*  spill_n = (int2*)(ib + I_SPN);

    float* out_v = (float*)d_out;                   // [50000, 64]
    float* out_e = (float*)d_out + (size_t)NN * 64; // [10000, 64]

    // ---- prep: zero cursors + attn folds + W transpose ----
    prep_kernel<<<dim3(66), dim3(256), 0, stream>>>(W_qe, attn_qe, cqe, W_qv, attn_qv, cqv,
                                                    W_ke, Wt, cur);

    // ---- phase1: hedge-binning || MFMA GEMM || er rows ----
    phase1_kernel<<<dim3(P1_GRID), dim3(256), 0, stream>>>(
        inc_n, inc_h, cur, csrH, spc_h, spill_h,
        vfeat, Wt, attn_ke, cqv, (unsigned short*)vke, el, er2,
        efeat, cqe, er);

    // ---- phase2: node-binning || gather1 + in-wave GEMV ----
    phase2_kernel<<<dim3(P2_GRID), dim3(256), 0, stream>>>(
        inc_n, inc_h, cur, csrN, spc_n, spill_n,
        csrH, vke, el, er, bias_e, spc_h, spill_h, out_e,
        W_kv, attn_kv, ekv, el2);

    // ---- final gather: hyperedges -> nodes ----
    gather_kernel<CAPN><<<dim3((NN + 3) / 4), dim3(256), 0, stream>>>(
        cur + NM, csrN, ekv, el2, er2, bias_v, spc_n, spill_n, out_v, NN);
}

// Round 12
// 135.131 us; speedup vs baseline: 1.3043x; 1.0371x over previous
//
#include <hip/hip_runtime.h>
#include <hip/hip_bf16.h>

#define NN 50000      // nodes
#define NM 10000      // hyperedges
#define NE 500000     // incidences
#define CAPH 128      // fixed bin capacity per hedge (mean 50, sd 7 -> 11 sd)
#define CAPN 32       // fixed bin capacity per node  (mean 10, sd 3.2 -> 7 sd)
#define SPCAP 4096    // spill safety list

// phase1: both-sides binning || MFMA GEMM || er rows
#define BIN_BLK   240
#define GEMM_TILES ((NN + 63) / 64)          // 782
#define ROWS_BLK  300
#define P1_GRID   (BIN_BLK + GEMM_TILES + ROWS_BLK)

typedef short bf16x8 __attribute__((ext_vector_type(8)));
typedef unsigned short u16x8 __attribute__((ext_vector_type(8)));
typedef float f32x4 __attribute__((ext_vector_type(4)));

// ---------------- workspace layout ----------------
// float-sized slots:
//   vke(bf16 u32x64/row) 3,200,000 @ 0
//   ekv(bf16 u32x64/row)   640,000 @ 3,200,000
//   el      100,000 @ 3,840,000
//   er       20,000 @ 3,940,000
//   el2      20,000 @ 3,960,000
//   er2     100,000 @ 3,980,000
//   cqe         256 @ 4,080,000
//   cqv         256 @ 4,080,256
//   Wt (bf16 16384)  8,192 float slots @ 4,080,512
// ints (base = float offset 4,089,000):
//   cur      60,000 @ 0   (hedge cursors then node cursors)
//   spc_h         1 @ 60,000
//   spc_n         1 @ 60,001
//   csrH  1,280,000 u16 = 640,000 int @ 60,004
//   csrN  1,600,000 u16 = 800,000 int @ 700,004
//   spill_h  4096 int2 = 8,192 int @ 1,500,004
//   spill_n  4096 int2 = 8,192 int @ 1,508,196
static const size_t OFF_VKE  = 0;
static const size_t OFF_EKV  = 3200000;
static const size_t OFF_EL   = 3840000;
static const size_t OFF_ER   = 3940000;
static const size_t OFF_EL2  = 3960000;
static const size_t OFF_ER2  = 3980000;
static const size_t OFF_CQE  = 4080000;
static const size_t OFF_CQV  = 4080256;
static const size_t OFF_WT   = 4080512;
static const size_t OFF_INT  = 4089000;
static const size_t I_CUR    = 0;
static const size_t I_SPCH   = 60000;
static const size_t I_SPCN   = 60001;
static const size_t I_CSRH   = 60004;
static const size_t I_CSRN   = 700004;
static const size_t I_SPH    = 1500004;
static const size_t I_SPN    = 1508196;

__device__ __forceinline__ unsigned short f2bf(float f) {
    unsigned int u = __float_as_uint(f);
    unsigned int r = (u + 0x7fffu + ((u >> 16) & 1u)) >> 16;   // RNE
    return (unsigned short)r;
}
__device__ __forceinline__ float bflo(unsigned int p) { return __uint_as_float(p << 16); }
__device__ __forceinline__ float bfhi(unsigned int p) { return __uint_as_float(p & 0xffff0000u); }

// ---- prep: zero cursors/spill counts; blocks 0,1 = attn folds; 2..65 = Wt transpose ----
__global__ void prep_kernel(const float* __restrict__ W_qe, const float* __restrict__ attn_qe,
                            float* __restrict__ cqe,
                            const float* __restrict__ W_qv, const float* __restrict__ attn_qv,
                            float* __restrict__ cqv,
                            const float* __restrict__ W_ke, unsigned short* __restrict__ Wt,
                            int* __restrict__ cur) {
    int b = blockIdx.x, t = threadIdx.x;     // 66 blocks x 256 threads
    for (int i = b * 256 + t; i < NM + NN + 2; i += 66 * 256) cur[i] = 0;
    if (b < 2) {
        const float* W    = b ? W_qv : W_qe;
        const float* attn = b ? attn_qv : attn_qe;
        float*       c    = b ? cqv : cqe;
        int h = t >> 7, k = t & 127;
        float s = 0.f;
        #pragma unroll 8
        for (int j = 0; j < 64; ++j) s += W[k * 128 + h * 64 + j] * attn[h * 64 + j];
        c[h * 128 + k] = s;
    } else {
        int col = (b - 2) * 2 + (t >> 7), k = t & 127;
        Wt[col * 128 + k] = f2bf(W_ke[k * 128 + col]);
    }
}

// ---- phase1 merged kernel: both-sides binning || MFMA GEMM+el+er2 || er rows ----
struct P1Smem {
    unsigned short Abuf[64 * 128];   // 16 KB
    unsigned short Wbuf[128 * 128];  // 32 KB
};

__global__ __launch_bounds__(256) void phase1_kernel(
        // bin role
        const int* __restrict__ inc_n, const int* __restrict__ inc_h,
        int* __restrict__ cur,
        unsigned short* __restrict__ csrH, unsigned short* __restrict__ csrN,
        int* __restrict__ spc_h, int2* __restrict__ spill_h,
        int* __restrict__ spc_n, int2* __restrict__ spill_n,
        // gemm role
        const float* __restrict__ X, const unsigned short* __restrict__ Wt,
        const float* __restrict__ attn, const float* __restrict__ cq,
        unsigned short* __restrict__ Y, float* __restrict__ el, float* __restrict__ er2,
        // rows_dot role
        const float* __restrict__ EF, const float* __restrict__ cqe,
        float* __restrict__ er) {
    __shared__ P1Smem sm;
    int bid = blockIdx.x, tid = threadIdx.x;

    if (bid < BIN_BLK) {
        // ===== both-sides binning: two dependent chains interleave (2x MLP) =====
        for (int t = bid * 256 + tid; t < NE; t += BIN_BLK * 256) {
            int n = inc_n[t], hd = inc_h[t];
            int rh = atomicAdd(&cur[hd], 1);
            if (rh < CAPH) csrH[hd * CAPH + rh] = (unsigned short)n;
            else { int s = atomicAdd(spc_h, 1); if (s < SPCAP) spill_h[s] = make_int2(hd, n); }
            int rn = atomicAdd(&cur[NM + n], 1);
            if (rn < CAPN) csrN[n * CAPN + rn] = (unsigned short)hd;
            else { int s = atomicAdd(spc_n, 1); if (s < SPCAP) spill_n[s] = make_int2(n, hd); }
        }
        return;
    }
    if (bid >= BIN_BLK + GEMM_TILES) {
        // ================= er rows: er[m][h] = EF[m,:].cqe[h,:] =================
        int wave = tid >> 6, lane = tid & 63;
        for (int g = bid - BIN_BLK - GEMM_TILES; g < (NM + 3) / 4; g += ROWS_BLK) {
            int m = g * 4 + wave;
            if (m < NM) {
                float x0 = EF[(size_t)m * 128 + lane];
                float x1 = EF[(size_t)m * 128 + 64 + lane];
                float a0 = x0 * cqe[lane]       + x1 * cqe[64 + lane];
                float a1 = x0 * cqe[128 + lane] + x1 * cqe[192 + lane];
                for (int off = 32; off > 0; off >>= 1) {
                    a0 += __shfl_down(a0, off);
                    a1 += __shfl_down(a1, off);
                }
                if (lane == 0) { er[m * 2] = a0; er[m * 2 + 1] = a1; }
            }
        }
        return;
    }

    // ================= MFMA GEMM tile =================
    int m0 = (bid - BIN_BLK) * 64;
    const int R = NN;
    // ---- stage W (bf16 global, coalesced) ----
    {
        const u16x8* Wg = reinterpret_cast<const u16x8*>(Wt);
        #pragma unroll
        for (int i = 0; i < 8; ++i) {
            int idx16 = i * 256 + tid;           // 2048 x 16B
            u16x8 w8 = Wg[idx16];
            int col = idx16 >> 4, kb = idx16 & 15;
            int us = (col * 128 + kb * 8) ^ ((col & 7) << 3);
            *reinterpret_cast<u16x8*>(&sm.Wbuf[us]) = w8;
        }
    }
    // ---- stage X (f32 -> bf16) + er2 partial dot with cq ----
    {
        int r = tid >> 2, q = tid & 3;           // 4 threads per row, 32 cols each
        int m = m0 + r;
        float p0 = 0.f, p1 = 0.f;
        if (m < R) {
            const float4* Xr = reinterpret_cast<const float4*>(X + (size_t)m * 128 + q * 32);
            #pragma unroll
            for (int i2 = 0; i2 < 4; ++i2) {
                float4 u = Xr[i2 * 2], v = Xr[i2 * 2 + 1];
                int k0 = q * 32 + i2 * 8;
                u16x8 w8;
                w8[0] = f2bf(u.x); w8[1] = f2bf(u.y); w8[2] = f2bf(u.z); w8[3] = f2bf(u.w);
                w8[4] = f2bf(v.x); w8[5] = f2bf(v.y); w8[6] = f2bf(v.z); w8[7] = f2bf(v.w);
                int us = (r * 128 + k0) ^ ((r & 7) << 3);
                *reinterpret_cast<u16x8*>(&sm.Abuf[us]) = w8;
                p0 += u.x * cq[k0] + u.y * cq[k0 + 1] + u.z * cq[k0 + 2] + u.w * cq[k0 + 3]
                    + v.x * cq[k0 + 4] + v.y * cq[k0 + 5] + v.z * cq[k0 + 6] + v.w * cq[k0 + 7];
                p1 += u.x * cq[128 + k0] + u.y * cq[128 + k0 + 1] + u.z * cq[128 + k0 + 2] + u.w * cq[128 + k0 + 3]
                    + v.x * cq[128 + k0 + 4] + v.y * cq[128 + k0 + 5] + v.z * cq[128 + k0 + 6] + v.w * cq[128 + k0 + 7];
            }
        } else {
            u16x8 z = {0, 0, 0, 0, 0, 0, 0, 0};
            #pragma unroll
            for (int i2 = 0; i2 < 4; ++i2) {
                int us = (r * 128 + q * 32 + i2 * 8) ^ ((r & 7) << 3);
                *reinterpret_cast<u16x8*>(&sm.Abuf[us]) = z;
            }
        }
        p0 += __shfl_xor(p0, 1); p0 += __shfl_xor(p0, 2);
        p1 += __shfl_xor(p1, 1); p1 += __shfl_xor(p1, 2);
        if (q == 0 && m < R)
            reinterpret_cast<float2*>(er2 + (size_t)m * 2)[0] = make_float2(p0, p1);
    }
    __syncthreads();

    // ---- MFMA: wave w -> rows [w*16, w*16+16), 8 col-tiles, 4 K-steps ----
    int l = tid & 63, w = tid >> 6;
    int lrow = w * 16 + (l & 15);
    f32x4 acc[8];
    #pragma unroll
    for (int ct = 0; ct < 8; ++ct) acc[ct] = (f32x4){0.f, 0.f, 0.f, 0.f};
    #pragma unroll
    for (int s = 0; s < 4; ++s) {
        int aidx = (lrow * 128 + s * 32 + (l >> 4) * 8) ^ ((lrow & 7) << 3);
        bf16x8 af = *reinterpret_cast<const bf16x8*>(&sm.Abuf[aidx]);
        #pragma unroll
        for (int ct = 0; ct < 8; ++ct) {
            int col = ct * 16 + (l & 15);
            int bidx = (col * 128 + s * 32 + (l >> 4) * 8) ^ ((col & 7) << 3);
            bf16x8 bf = *reinterpret_cast<const bf16x8*>(&sm.Wbuf[bidx]);
            acc[ct] = __builtin_amdgcn_mfma_f32_16x16x32_bf16(af, bf, acc[ct], 0, 0, 0);
        }
    }

    // ---- epilogue: Y bf16 store, el reduce ----
    float av[8];
    #pragma unroll
    for (int ct = 0; ct < 8; ++ct) av[ct] = attn[ct * 16 + (l & 15)];
    #pragma unroll
    for (int r = 0; r < 4; ++r) {
        int m = m0 + w * 16 + (l >> 4) * 4 + r;
        bool ok = (m < R);
        #pragma unroll
        for (int ct = 0; ct < 8; ++ct)
            if (ok) Y[(size_t)m * 128 + ct * 16 + (l & 15)] = f2bf(acc[ct][r]);
        #pragma unroll
        for (int h = 0; h < 2; ++h) {
            float p = acc[h * 4][r] * av[h * 4] + acc[h * 4 + 1][r] * av[h * 4 + 1]
                    + acc[h * 4 + 2][r] * av[h * 4 + 2] + acc[h * 4 + 3][r] * av[h * 4 + 3];
            p += __shfl_xor(p, 1); p += __shfl_xor(p, 2);
            p += __shfl_xor(p, 4); p += __shfl_xor(p, 8);
            if ((l & 15) == 0 && ok) el[(size_t)m * 2 + h] = p;
        }
    }
}

// ---- gather1 + in-wave GEMV (ekv, el2): one wave per hedge, grid exact ----
__global__ __launch_bounds__(256) void gather1_kernel(
        const int* __restrict__ cur,
        const unsigned short* __restrict__ csrH,
        const unsigned int* __restrict__ vke32,
        const float* __restrict__ el, const float* __restrict__ er,
        const float* __restrict__ bias_e,
        const int* __restrict__ spc_h, const int2* __restrict__ spill_h,
        float* __restrict__ out_e,
        const float* __restrict__ W_kv, const float* __restrict__ attn_kv,
        unsigned int* __restrict__ ekv32, float* __restrict__ el2) {
    int tid = threadIdx.x;
    int wave = tid >> 6, lane = tid & 63;
    int m = blockIdx.x * 4 + wave;                // < NM (grid exact)
    int h = lane >> 5;
    int c = cur[m]; if (c > CAPH) c = CAPH;
    int beg = m * CAPH, end = beg + c;
    float erv = er[m * 2 + h];
    float acc0 = 0.f, acc1 = 0.f, den = 0.f;
    int i = beg;
    for (; i + 3 < end; i += 4) {
        int vs0 = csrH[i], vs1 = csrH[i + 1], vs2 = csrH[i + 2], vs3 = csrH[i + 3];
        unsigned int p0 = vke32[(size_t)vs0 * 64 + lane];
        unsigned int p1 = vke32[(size_t)vs1 * 64 + lane];
        unsigned int p2 = vke32[(size_t)vs2 * 64 + lane];
        unsigned int p3 = vke32[(size_t)vs3 * 64 + lane];
        float ex0 = __expf(fmaxf(el[vs0 * 2 + h] + erv, 0.f));
        float ex1 = __expf(fmaxf(el[vs1 * 2 + h] + erv, 0.f));
        float ex2 = __expf(fmaxf(el[vs2 * 2 + h] + erv, 0.f));
        float ex3 = __expf(fmaxf(el[vs3 * 2 + h] + erv, 0.f));
        den += (ex0 + ex1) + (ex2 + ex3);
        acc0 += ex0 * bflo(p0) + ex1 * bflo(p1) + ex2 * bflo(p2) + ex3 * bflo(p3);
        acc1 += ex0 * bfhi(p0) + ex1 * bfhi(p1) + ex2 * bfhi(p2) + ex3 * bfhi(p3);
    }
    for (; i < end; ++i) {
        int vs = csrH[i];
        unsigned int p = vke32[(size_t)vs * 64 + lane];
        float ex = __expf(fmaxf(el[vs * 2 + h] + erv, 0.f));
        den += ex;
        acc0 += ex * bflo(p);
        acc1 += ex * bfhi(p);
    }
    // spill safety (expected empty)
    int sc = *spc_h; if (sc > SPCAP) sc = SPCAP;
    for (int s = 0; s < sc; ++s) {
        int2 pr = spill_h[s];
        if (pr.x == m) {
            int vs = pr.y;
            unsigned int p = vke32[(size_t)vs * 64 + lane];
            float ex = __expf(fmaxf(el[vs * 2 + h] + erv, 0.f));
            den += ex;
            acc0 += ex * bflo(p);
            acc1 += ex * bfhi(p);
        }
    }
    float inv = (den > 0.f) ? 1.f / den : 0.f;
    acc0 *= inv; acc1 *= inv;
    float b0 = __shfl_down(acc0, 32);
    float b1 = __shfl_down(acc1, 32);
    int e0 = 2 * (lane & 31), e1 = e0 + 1;
    // o0/o1 meaningful only in lanes<32 (row cols e0,e1)
    float o0 = 0.5f * (acc0 + b0 + bias_e[e0] + bias_e[64 + e0]);
    float o1 = 0.5f * (acc1 + b1 + bias_e[e1] + bias_e[64 + e1]);
    if (lane < 32)
        reinterpret_cast<float2*>(out_e + (size_t)m * 64)[lane] = make_float2(o0, o1);

    // ---- in-wave GEMV: ekv[m][2l,2l+1] = sum_k row[k] * W_kv[k][2l,2l+1] ----
    const float2* Wkv2 = reinterpret_cast<const float2*>(W_kv);
    float g0 = 0.f, g1 = 0.f;
    #pragma unroll
    for (int k = 0; k < 64; ++k) {
        float rk = __shfl((k & 1) ? o1 : o0, k >> 1);   // row[k] from lane k/2
        float2 wv = Wkv2[k * 64 + lane];
        g0 += rk * wv.x;
        g1 += rk * wv.y;
    }
    ekv32[(size_t)m * 64 + lane] = ((unsigned int)f2bf(g1) << 16) | (unsigned int)f2bf(g0);
    // el2[m][h] over cols 2l,2l+1 (head = lane>>5); reduce within 32-lane half
    float p = g0 * attn_kv[2 * lane] + g1 * attn_kv[2 * lane + 1];
    p += __shfl_xor(p, 1); p += __shfl_xor(p, 2); p += __shfl_xor(p, 4);
    p += __shfl_xor(p, 8); p += __shfl_xor(p, 16);
    if ((lane & 31) == 0) el2[m * 2 + (lane >> 5)] = p;
}

// ---- final gather over node bins: wave/dest, 4-way MLP unroll ----
template<int CAP>
__global__ void gather_kernel(const int* __restrict__ cnt, const unsigned short* __restrict__ csr,
                              const unsigned int* __restrict__ src32,  // [*,64] bf16x2
                              const float* __restrict__ el_src,        // [*,2]
                              const float* __restrict__ er_dst,        // [R,2]
                              const float* __restrict__ bias,          // [128]
                              const int* __restrict__ spc, const int2* __restrict__ spill,
                              float* __restrict__ out, int R) {
    int wave = threadIdx.x >> 6, lane = threadIdx.x & 63;
    int m = blockIdx.x * 4 + wave;
    if (m >= R) return;
    int h = lane >> 5;
    int c = cnt[m]; if (c > CAP) c = CAP;
    int beg = m * CAP, end = beg + c;
    float er = er_dst[m * 2 + h];
    float acc0 = 0.f, acc1 = 0.f, den = 0.f;
    int i = beg;
    for (; i + 3 < end; i += 4) {
        int vs0 = csr[i], vs1 = csr[i + 1], vs2 = csr[i + 2], vs3 = csr[i + 3];
        unsigned int p0 = src32[(size_t)vs0 * 64 + lane];
        unsigned int p1 = src32[(size_t)vs1 * 64 + lane];
        unsigned int p2 = src32[(size_t)vs2 * 64 + lane];
        unsigned int p3 = src32[(size_t)vs3 * 64 + lane];
        float ex0 = __expf(fmaxf(el_src[vs0 * 2 + h] + er, 0.f));
        float ex1 = __expf(fmaxf(el_src[vs1 * 2 + h] + er, 0.f));
        float ex2 = __expf(fmaxf(el_src[vs2 * 2 + h] + er, 0.f));
        float ex3 = __expf(fmaxf(el_src[vs3 * 2 + h] + er, 0.f));
        den += (ex0 + ex1) + (ex2 + ex3);
        acc0 += ex0 * bflo(p0) + ex1 * bflo(p1) + ex2 * bflo(p2) + ex3 * bflo(p3);
        acc1 += ex0 * bfhi(p0) + ex1 * bfhi(p1) + ex2 * bfhi(p2) + ex3 * bfhi(p3);
    }
    for (; i < end; ++i) {
        int vs = csr[i];
        unsigned int p = src32[(size_t)vs * 64 + lane];
        float ex = __expf(fmaxf(el_src[vs * 2 + h] + er, 0.f));
        den += ex;
        acc0 += ex * bflo(p);
        acc1 += ex * bfhi(p);
    }
    int sc = *spc; if (sc > SPCAP) sc = SPCAP;
    for (int s = 0; s < sc; ++s) {
        int2 pr = spill[s];
        if (pr.x == m) {
            int vs = pr.y;
            unsigned int p = src32[(size_t)vs * 64 + lane];
            float ex = __expf(fmaxf(el_src[vs * 2 + h] + er, 0.f));
            den += ex;
            acc0 += ex * bflo(p);
            acc1 += ex * bfhi(p);
        }
    }
    float inv = (den > 0.f) ? 1.f / den : 0.f;
    acc0 *= inv; acc1 *= inv;
    float b0 = __shfl_down(acc0, 32);
    float b1 = __shfl_down(acc1, 32);
    if (lane < 32) {
        int e0 = 2 * lane, e1 = 2 * lane + 1;
        float o0 = 0.5f * (acc0 + b0 + bias[e0] + bias[64 + e0]);
        float o1 = 0.5f * (acc1 + b1 + bias[e1] + bias[64 + e1]);
        reinterpret_cast<float2*>(out + (size_t)m * 64)[lane] = make_float2(o0, o1);
    }
}

extern "C" void kernel_launch(void* const* d_in, const int* in_sizes, int n_in,
                              void* d_out, int out_size, void* d_ws, size_t ws_size,
                              hipStream_t stream) {
    const float* vfeat   = (const float*)d_in[0];
    const float* efeat   = (const float*)d_in[1];
    const int*   inc_n   = (const int*)d_in[2];
    const int*   inc_h   = (const int*)d_in[3];
    const float* W_ke    = (const float*)d_in[4];
    const float* W_qe    = (const float*)d_in[5];
    const float* attn_ke = (const float*)d_in[6];
    const float* attn_qe = (const float*)d_in[7];
    const float* bias_e  = (const float*)d_in[8];
    const float* W_kv    = (const float*)d_in[9];
    const float* W_qv    = (const float*)d_in[10];
    const float* attn_kv = (const float*)d_in[11];
    const float* attn_qv = (const float*)d_in[12];
    const float* bias_v  = (const float*)d_in[13];

    float* ws = (float*)d_ws;
    unsigned int*   vke = (unsigned int*)(ws + OFF_VKE);
    unsigned int*   ekv = (unsigned int*)(ws + OFF_EKV);
    float* el   = ws + OFF_EL;
    float* er   = ws + OFF_ER;
    float* el2  = ws + OFF_EL2;
    float* er2  = ws + OFF_ER2;
    float* cqe  = ws + OFF_CQE;
    float* cqv  = ws + OFF_CQV;
    unsigned short* Wt = (unsigned short*)(ws + OFF_WT);
    int*   ib      = (int*)(ws + OFF_INT);
    int*   cur     = ib + I_CUR;
    int*   spc_h   = ib + I_SPCH;
    int*   spc_n   = ib + I_SPCN;
    unsigned short* csrH = (unsigned short*)(ib + I_CSRH);
    unsigned short* csrN = (unsigned short*)(ib + I_CSRN);
    int2*  spill_h = (int2*)(ib + I_SPH);
    int2*  spill_n = (int2*)(ib + I_SPN);

    float* out_v = (float*)d_out;                   // [50000, 64]
    float* out_e = (float*)d_out + (size_t)NN * 64; // [10000, 64]

    // ---- prep: zero cursors + attn folds + W transpose ----
    prep_kernel<<<dim3(66), dim3(256), 0, stream>>>(W_qe, attn_qe, cqe, W_qv, attn_qv, cqv,
                                                    W_ke, Wt, cur);

    // ---- phase1: both-sides binning || MFMA GEMM || er rows ----
    phase1_kernel<<<dim3(P1_GRID), dim3(256), 0, stream>>>(
        inc_n, inc_h, cur, csrH, csrN, spc_h, spill_h, spc_n, spill_n,
        vfeat, Wt, attn_ke, cqv, (unsigned short*)vke, el, er2,
        efeat, cqe, er);

    // ---- gather1 + in-wave GEMV ----
    gather1_kernel<<<dim3(NM / 4), dim3(256), 0, stream>>>(
        cur, csrH, vke, el, er, bias_e, spc_h, spill_h, out_e,
        W_kv, attn_kv, ekv, el2);

    // ---- final gather: hyperedges -> nodes ----
    gather_kernel<CAPN><<<dim3((NN + 3) / 4), dim3(256), 0, stream>>>(
        cur + NM, csrN, ekv, el2, er2, bias_v, spc_n, spill_n, out_v, NN);
}